// Round 9
// baseline (1515.198 us; speedup 1.0000x reference)
//
#include <hip/hip_runtime.h>

// GCN 2-layer + BatchNorm1d forward.
// R9: buildC+agg64 fused into aggF: one block per bucket (128 nodes), f32 LDS
//     accumulator acc[128][65] (pad kills stride-64 bank aliasing), edge-
//     parallel sweep of the bucket's contiguous ebuf window with LDS
//     atomicAdd(f32). Kills: buildC's extra edge pass + srcs/start arrays +
//     agg64's degree-variance wave imbalance (wave waited on max of 4 node
//     degrees). deg_k (per-bucket count) now produces dis. Layer-2 aggF also
//     emits per-bucket BN partial sums -> bn_part kernel deleted.
// Kept: layer-1 commute A(XW)=(AX)W (gathers on 64-dim fp16 rows, f32 accum),
//     counting-sort CSR front-end (hist/scan_bucket/scan_total/scatB),
//     dot2 GEMMs, atomic-free BN finalize.
// Pipeline: hist -> scan_bucket -> scan_total -> scatB -> deg
//   -> prescale es=fp16(dis*emb) -> aggF ag1 -> gemmA t1 -> gemmB hs2
//   -> aggF h2 (+BN partials) -> bn_final -> bn_apply -> d_out f32.

#define EPS_BN 1e-5f
#define NBKT_PAD 1024   // >= ceil(N/128); N=100000 -> 782 buckets
#define SCAT_B 256      // edge-pass blocks (1024 threads each)

typedef _Float16 f16;
typedef _Float16 f16x2 __attribute__((ext_vector_type(2)));
union pk4 { ushort4 u; f16 h[4]; f16x2 h2[2]; };

#if __has_builtin(__builtin_amdgcn_fdot2)
__device__ __forceinline__ float fdot2(f16x2 a, f16x2 b, float c) {
    return __builtin_amdgcn_fdot2(a, b, c, false);
}
#else
__device__ __forceinline__ float fdot2(f16x2 a, f16x2 b, float c) {
    return c + (float)a[0] * (float)b[0] + (float)a[1] * (float)b[1];
}
#endif

// ---------------- hist: per-block bucket histogram -> ghist ----------------
__global__ __launch_bounds__(1024) void hist_k(const int* __restrict__ colv, int E, int epb,
                                               int* __restrict__ ghist) {
    __shared__ int bins[NBKT_PAD];
    int tid = threadIdx.x;
    bins[tid] = 0;
    __syncthreads();
    int e0 = blockIdx.x * epb;
    int e1 = min(E, e0 + epb);
    for (int e = e0 + tid; e < e1; e += 1024)
        atomicAdd(&bins[colv[e] >> 7], 1);
    __syncthreads();
    ghist[blockIdx.x * NBKT_PAD + tid] = bins[tid];
}

// ---------------- scan_bucket: per-bucket exclusive prefix over the 256 blocks ----------------
__global__ __launch_bounds__(256) void scan_bucket_k(int* __restrict__ ghist, int* __restrict__ bcnt) {
    __shared__ int s[256];
    int k = blockIdx.x;
    int b = threadIdx.x;
    int v = ghist[b * NBKT_PAD + k];
    s[b] = v; __syncthreads();
    for (int off = 1; off < 256; off <<= 1) {
        int t = (b >= off) ? s[b - off] : 0;
        __syncthreads();
        s[b] += t;
        __syncthreads();
    }
    ghist[b * NBKT_PAD + k] = s[b] - v;           // exclusive within bucket
    if (b == 255) bcnt[k] = s[255];
}

// ---------------- scan_total: exclusive scan of bucket totals ----------------
__global__ __launch_bounds__(1024) void scan_total_k(const int* __restrict__ bcnt,
                                                     int* __restrict__ bstart, int E) {
    __shared__ int s[1024];
    int tid = threadIdx.x;
    int v = bcnt[tid];
    s[tid] = v; __syncthreads();
    for (int off = 1; off < 1024; off <<= 1) {
        int t = (tid >= off) ? s[tid - off] : 0;
        __syncthreads();
        s[tid] += t;
        __syncthreads();
    }
    bstart[tid] = s[tid] - v;
    if (tid == 1023) bstart[1024] = s[1023];
}

// ---------------- scatB: single-pass scatter (cursor = ghist + bstart) ----------------
__global__ __launch_bounds__(1024) void scatB_k(const int* __restrict__ rowv, const int* __restrict__ colv,
                                                int E, int epb, const int* __restrict__ ghist,
                                                const int* __restrict__ bstart,
                                                unsigned* __restrict__ ebuf) {
    __shared__ int bins[NBKT_PAD];
    int tid = threadIdx.x;
    bins[tid] = ghist[blockIdx.x * NBKT_PAD + tid] + bstart[tid];
    __syncthreads();
    int e0 = blockIdx.x * epb;
    int e1 = min(E, e0 + epb);
    for (int e = e0 + tid; e < e1; e += 1024) {
        int c = colv[e];
        int p = atomicAdd(&bins[c >> 7], 1);
        ebuf[p] = ((unsigned)rowv[e] << 7) | (unsigned)(c & 127);
    }
}

// ---------------- deg: per-bucket node degree -> dis ----------------
__global__ __launch_bounds__(256) void deg_k(const unsigned* __restrict__ ebuf,
                                             const int* __restrict__ bstart,
                                             float* __restrict__ dis, int n) {
    __shared__ int cnt[128];
    int b = blockIdx.x, tid = threadIdx.x;
    if (tid < 128) cnt[tid] = 0;
    __syncthreads();
    int e0 = bstart[b], e1 = bstart[b + 1];
    for (int e = e0 + tid; e < e1; e += 256)
        atomicAdd(&cnt[ebuf[e] & 127u], 1);
    __syncthreads();
    int node = b * 128 + tid;
    if (tid < 128 && node < n)
        dis[node] = rsqrtf((float)(cnt[tid] + 1));        // +1 self-loop
}

// ---------------- prescale: es = fp16(dis * emb), 64-dim ----------------
__global__ __launch_bounds__(256) void prescale_k(const float* __restrict__ emb,
                                                  const float* __restrict__ dis,
                                                  f16* __restrict__ es, int n) {
    int gid = blockIdx.x * 256 + threadIdx.x;
    int node = gid >> 4, q = gid & 15;
    if (node >= n) return;
    float d = dis[node];
    float4 v = ((const float4*)emb)[(size_t)node * 16 + q];
    pk4 p;
    p.h[0] = (f16)(v.x * d); p.h[1] = (f16)(v.y * d);
    p.h[2] = (f16)(v.z * d); p.h[3] = (f16)(v.w * d);
    ((ushort4*)es)[(size_t)node * 16 + q] = p.u;
}

// ---------------- aggF: fused per-bucket aggregation (edge-parallel, LDS f32 acc) ----------------
// out[node] = fp16(dis[node] * (table[node] + Σ_src table[src]) + bias)
// If pbuf != null, also emits per-bucket BN partials: pbuf[b][0..63]=Σout, [64..127]=Σout².
__global__ __launch_bounds__(256) void aggF_k(const f16* __restrict__ table,
                                              const unsigned* __restrict__ ebuf,
                                              const int* __restrict__ bstart,
                                              const float* __restrict__ dis,
                                              const float* __restrict__ bias,
                                              f16* __restrict__ out,
                                              float* __restrict__ pbuf, int n) {
    __shared__ float acc[128 * 65];               // [loc][65] pad: bank = (loc+4q+j)%32
    int b = blockIdx.x, tid = threadIdx.x;
    int base = b * 128;
    const ushort4* t4 = (const ushort4*)table;
    // init: self-loop rows
    for (int i = tid; i < 2048; i += 256) {       // 128 rows x 16 quads
        int r = i >> 4, q = i & 15;
        int node = base + r;
        ushort4 u = make_ushort4(0, 0, 0, 0);
        if (node < n) u = t4[(size_t)node * 16 + q];
        pk4 p; p.u = u;
        float* dst = &acc[r * 65 + q * 4];
        dst[0] = p.h[0]; dst[1] = p.h[1]; dst[2] = p.h[2]; dst[3] = p.h[3];
    }
    __syncthreads();
    int e0 = bstart[b], e1 = bstart[b + 1];
    int q = tid & 15, g = tid >> 4;               // 16 edge-groups x 16 dim-lanes
    int nE = e1 - e0;
    int nChunk = nE >> 7;                         // 128-edge chunks (16 groups x 8)
    for (int it = 0; it < nChunk; ++it) {
        int eb = e0 + it * 128 + g * 8;
        unsigned pp[8];
#pragma unroll
        for (int j = 0; j < 8; j++) pp[j] = ebuf[eb + j];
        pk4 v[8];
#pragma unroll
        for (int j = 0; j < 8; j++) v[j].u = t4[(size_t)(pp[j] >> 7) * 16 + q];
#pragma unroll
        for (int j = 0; j < 8; j++) {
            float* dst = &acc[(pp[j] & 127u) * 65 + q * 4];
            atomicAdd(dst + 0, (float)v[j].h[0]);
            atomicAdd(dst + 1, (float)v[j].h[1]);
            atomicAdd(dst + 2, (float)v[j].h[2]);
            atomicAdd(dst + 3, (float)v[j].h[3]);
        }
    }
    for (int e = e0 + nChunk * 128 + g; e < e1; e += 16) {   // tail
        unsigned p = ebuf[e];
        pk4 v; v.u = t4[(size_t)(p >> 7) * 16 + q];
        float* dst = &acc[(p & 127u) * 65 + q * 4];
        atomicAdd(dst + 0, (float)v.h[0]);
        atomicAdd(dst + 1, (float)v.h[1]);
        atomicAdd(dst + 2, (float)v.h[2]);
        atomicAdd(dst + 3, (float)v.h[3]);
    }
    __syncthreads();
    // epilogue: group g handles rows g*8..g*8+7, dims 4q..4q+3
    float4 s = make_float4(0.f, 0.f, 0.f, 0.f);
    float4 sq = make_float4(0.f, 0.f, 0.f, 0.f);
    float4 bb = make_float4(0.f, 0.f, 0.f, 0.f);
    if (bias) bb = ((const float4*)bias)[q];
#pragma unroll
    for (int rr = 0; rr < 8; rr++) {
        int r = g * 8 + rr;
        int node = base + r;
        if (node < n) {
            float d = dis[node];
            float* sp = &acc[r * 65 + q * 4];
            float4 o;
            o.x = sp[0] * d + bb.x; o.y = sp[1] * d + bb.y;
            o.z = sp[2] * d + bb.z; o.w = sp[3] * d + bb.w;
            pk4 ph;
            ph.h[0] = (f16)o.x; ph.h[1] = (f16)o.y; ph.h[2] = (f16)o.z; ph.h[3] = (f16)o.w;
            ((ushort4*)out)[(size_t)node * 16 + q] = ph.u;
            if (pbuf) {
                s.x += o.x; s.y += o.y; s.z += o.z; s.w += o.w;
                sq.x += o.x * o.x; sq.y += o.y * o.y; sq.z += o.z * o.z; sq.w += o.w * o.w;
            }
        }
    }
    if (pbuf) {
        __syncthreads();
        float4* red = (float4*)acc;               // reuse LDS
        red[tid] = s; red[256 + tid] = sq;
        __syncthreads();
        if (tid < 16) {
            float4 S = make_float4(0.f, 0.f, 0.f, 0.f);
            float4 Q = make_float4(0.f, 0.f, 0.f, 0.f);
            for (int gg = 0; gg < 16; gg++) {
                float4 a = red[gg * 16 + tid], c = red[256 + gg * 16 + tid];
                S.x += a.x; S.y += a.y; S.z += a.z; S.w += a.w;
                Q.x += c.x; Q.y += c.y; Q.z += c.z; Q.w += c.w;
            }
            float4* dst = (float4*)(pbuf + (size_t)b * 128);
            dst[tid] = S;
            dst[16 + tid] = Q;
        }
    }
}

// ---------------- gemmA: t1 = fp16(ag1[n,64] @ W1[64,128] + b1) ----------------
__global__ __launch_bounds__(256) void gemmA_k(const f16* __restrict__ ag1, const float* __restrict__ W1,
                                               const float* __restrict__ b1, f16* __restrict__ t1, int n) {
    __shared__ f16x2 sW[32 * 128];    // [kk][c] = (W1[2kk][c], W1[2kk+1][c])
    __shared__ f16x2 sA[32 * 34];     // [r][kk], padded
    int tid = threadIdx.x;
    for (int i = tid; i < 32 * 128; i += 256) {
        int kk = i >> 7, c = i & 127;
        f16x2 w; w[0] = (f16)W1[(2 * kk) * 128 + c]; w[1] = (f16)W1[(2 * kk + 1) * 128 + c];
        sW[i] = w;
    }
    int rowbase = blockIdx.x * 32;
    for (int i = tid; i < 512; i += 256) {            // 32 rows x 16 ushort4
        int r = i >> 4, q = i & 15;
        int gr = rowbase + r;
        ushort4 u = make_ushort4(0, 0, 0, 0);
        if (gr < n) u = ((const ushort4*)ag1)[(size_t)gr * 16 + q];
        ((ushort4*)sA)[r * 17 + q] = u;
    }
    __syncthreads();
    int L = tid & 31, rg = tid >> 5;                  // cols 4L..4L+3, rows rg*4..+3
    float acc[4][4] = {};
#pragma unroll 4
    for (int kk = 0; kk < 32; kk++) {
        f16x2 w0 = sW[kk * 128 + 4 * L];
        f16x2 w1 = sW[kk * 128 + 4 * L + 1];
        f16x2 w2 = sW[kk * 128 + 4 * L + 2];
        f16x2 w3 = sW[kk * 128 + 4 * L + 3];
#pragma unroll
        for (int rr = 0; rr < 4; rr++) {
            f16x2 a = sA[(rg * 4 + rr) * 34 + kk];
            acc[rr][0] = fdot2(a, w0, acc[rr][0]);
            acc[rr][1] = fdot2(a, w1, acc[rr][1]);
            acc[rr][2] = fdot2(a, w2, acc[rr][2]);
            acc[rr][3] = fdot2(a, w3, acc[rr][3]);
        }
    }
    float4 bb = *(const float4*)(b1 + 4 * L);
#pragma unroll
    for (int rr = 0; rr < 4; rr++) {
        int row = rowbase + rg * 4 + rr;
        if (row < n) {
            pk4 p;
            p.h[0] = (f16)(acc[rr][0] + bb.x); p.h[1] = (f16)(acc[rr][1] + bb.y);
            p.h[2] = (f16)(acc[rr][2] + bb.z); p.h[3] = (f16)(acc[rr][3] + bb.w);
            ((ushort4*)t1)[(size_t)row * 32 + L] = p.u;
        }
    }
}

// ---------------- gemmB: hs2 = fp16(dis * (t1[n,128] @ W2[128,64])) ----------------
__global__ __launch_bounds__(256) void gemmB_k(const f16* __restrict__ t1, const float* __restrict__ W2,
                                               const float* __restrict__ dis, f16* __restrict__ hs2, int n) {
    __shared__ f16x2 sW[64 * 64];     // [kk][c] = (W2[2kk][c], W2[2kk+1][c])
    __shared__ f16x2 sA[64 * 66];     // [r][kk], padded (+2)
    int tid = threadIdx.x;
    for (int i = tid; i < 64 * 64; i += 256) {
        int kk = i >> 6, c = i & 63;
        f16x2 w; w[0] = (f16)W2[(2 * kk) * 64 + c]; w[1] = (f16)W2[(2 * kk + 1) * 64 + c];
        sW[i] = w;
    }
    int rowbase = blockIdx.x * 64;
    for (int i = tid; i < 2048; i += 256) {           // 64 rows x 32 ushort4
        int r = i >> 5, q = i & 31;
        int gr = rowbase + r;
        ushort4 u = make_ushort4(0, 0, 0, 0);
        if (gr < n) u = ((const ushort4*)t1)[(size_t)gr * 32 + q];
        ((ushort4*)sA)[r * 33 + q] = u;
    }
    __syncthreads();
    int L = tid & 15, rg = tid >> 4;                  // cols 4L..4L+3, rows rg*4..+3
    float acc[4][4] = {};
#pragma unroll 4
    for (int kk = 0; kk < 64; kk++) {
        f16x2 w0 = sW[kk * 64 + 4 * L];
        f16x2 w1 = sW[kk * 64 + 4 * L + 1];
        f16x2 w2 = sW[kk * 64 + 4 * L + 2];
        f16x2 w3 = sW[kk * 64 + 4 * L + 3];
#pragma unroll
        for (int rr = 0; rr < 4; rr++) {
            f16x2 a = sA[(rg * 4 + rr) * 66 + kk];
            acc[rr][0] = fdot2(a, w0, acc[rr][0]);
            acc[rr][1] = fdot2(a, w1, acc[rr][1]);
            acc[rr][2] = fdot2(a, w2, acc[rr][2]);
            acc[rr][3] = fdot2(a, w3, acc[rr][3]);
        }
    }
#pragma unroll
    for (int rr = 0; rr < 4; rr++) {
        int row = rowbase + rg * 4 + rr;
        if (row < n) {
            float d = dis[row];
            pk4 p;
            p.h[0] = (f16)(acc[rr][0] * d); p.h[1] = (f16)(acc[rr][1] * d);
            p.h[2] = (f16)(acc[rr][2] * d); p.h[3] = (f16)(acc[rr][3] * d);
            ((ushort4*)hs2)[(size_t)row * 16 + L] = p.u;
        }
    }
}

// ---------------- bn_final: reduce nb per-bucket partials -> scale/shift ----------------
__global__ __launch_bounds__(256) void bn_final_k(const float* __restrict__ pbuf,
                                                  const float* __restrict__ gamma,
                                                  const float* __restrict__ beta,
                                                  int n, int nb,
                                                  float* __restrict__ scale, float* __restrict__ shift) {
    __shared__ float ls[256], lq[256];
    int c = threadIdx.x & 63, part = threadIdx.x >> 6;    // 4 slices
    float s = 0.f, q = 0.f;
    for (int b = part; b < nb; b += 4) {
        s += pbuf[(size_t)b * 128 + c];
        q += pbuf[(size_t)b * 128 + 64 + c];
    }
    ls[threadIdx.x] = s; lq[threadIdx.x] = q;
    __syncthreads();
    if (threadIdx.x < 64) {
        s = ls[c] + ls[c + 64] + ls[c + 128] + ls[c + 192];
        q = lq[c] + lq[c + 64] + lq[c + 128] + lq[c + 192];
        float inv_n = 1.f / (float)n;
        float mean = s * inv_n;
        float var = q * inv_n - mean * mean;      // biased variance
        float sc = gamma[c] * rsqrtf(var + EPS_BN);
        scale[c] = sc;
        shift[c] = beta[c] - mean * sc;
    }
}

// ---------------- bn_apply: h2 fp16 -> d_out f32 ----------------
__global__ __launch_bounds__(256) void bn_apply_k(const f16* __restrict__ x, const float* __restrict__ scale,
                                                  const float* __restrict__ shift, float* __restrict__ out, int n) {
    __shared__ float sscale[64], sshift[64];
    if (threadIdx.x < 64) {
        sscale[threadIdx.x] = scale[threadIdx.x];
        sshift[threadIdx.x] = shift[threadIdx.x];
    }
    __syncthreads();
    int i = blockIdx.x * 256 + threadIdx.x;
    if (i < n * 16) {
        int c = (i & 15) * 4;
        pk4 p; p.u = ((const ushort4*)x)[i];
        float4 o;
        o.x = (float)p.h[0] * sscale[c]     + sshift[c];
        o.y = (float)p.h[1] * sscale[c + 1] + sshift[c + 1];
        o.z = (float)p.h[2] * sscale[c + 2] + sshift[c + 2];
        o.w = (float)p.h[3] * sscale[c + 3] + sshift[c + 3];
        ((float4*)out)[i] = o;
    }
}

extern "C" void kernel_launch(void* const* d_in, const int* in_sizes, int n_in,
                              void* d_out, int out_size, void* d_ws, size_t ws_size,
                              hipStream_t stream) {
    const float* emb   = (const float*)d_in[0];
    const float* W1    = (const float*)d_in[1];
    const float* b1    = (const float*)d_in[2];
    const float* W2    = (const float*)d_in[3];
    const float* b2    = (const float*)d_in[4];
    const float* gamma = (const float*)d_in[5];
    const float* beta  = (const float*)d_in[6];
    const int*   ei    = (const int*)d_in[7];     // [2,E] int32
    const int n = in_sizes[0] / 64;               // 100000
    const int E = in_sizes[7] / 2;                // 1600000
    const int* rowv = ei;                         // sources
    const int* colv = ei + E;                     // targets
    const int NBKT = (n + 127) / 128;             // 782

    char* ws = (char*)d_ws;
    size_t o = 0;
    auto alloc = [&](size_t bytes) -> char* {
        char* p = ws + o;
        o = (o + bytes + 255) & ~(size_t)255;
        return p;
    };
    int*   ghist   = (int*)alloc((size_t)SCAT_B * NBKT_PAD * 4);  // 1MB
    int*   bcnt    = (int*)alloc(NBKT_PAD * 4);
    int*   bstart  = (int*)alloc((NBKT_PAD + 1) * 4);
    float* dis     = (float*)alloc((size_t)n * 4);
    float* pbuf    = (float*)alloc((size_t)NBKT * 128 * 4);       // per-bucket BN partials
    float* bnscale = (float*)alloc(256);
    float* bnshift = (float*)alloc(256);
    f16*   es      = (f16*)alloc((size_t)n * 64 * 2);    // dis*emb fp16
    f16*   ag1     = (f16*)alloc((size_t)n * 64 * 2);    // layer-1 aggregated
    f16*   t1      = (f16*)alloc((size_t)n * 128 * 2);   // h1 = ag1@W1+b1
    f16*   hs2     = (f16*)alloc((size_t)n * 64 * 2);    // dis*(t1@W2)
    f16*   h2      = (f16*)alloc((size_t)n * 64 * 2);    // pre-BN output
    unsigned* ebuf = (unsigned*)alloc((size_t)E * 4);    // packed bucket edges

    int epb = (E + SCAT_B - 1) / SCAT_B;          // 6250

    hist_k<<<SCAT_B, 1024, 0, stream>>>(colv, E, epb, ghist);
    scan_bucket_k<<<NBKT_PAD, 256, 0, stream>>>(ghist, bcnt);
    scan_total_k<<<1, 1024, 0, stream>>>(bcnt, bstart, E);
    scatB_k<<<SCAT_B, 1024, 0, stream>>>(rowv, colv, E, epb, ghist, bstart, ebuf);
    deg_k<<<NBKT, 256, 0, stream>>>(ebuf, bstart, dis, n);

    prescale_k<<<(n * 16 + 255) / 256, 256, 0, stream>>>(emb, dis, es, n);
    aggF_k<<<NBKT, 256, 0, stream>>>(es, ebuf, bstart, dis, nullptr, ag1, nullptr, n);
    gemmA_k<<<(n + 31) / 32, 256, 0, stream>>>(ag1, W1, b1, t1, n);
    gemmB_k<<<(n + 63) / 64, 256, 0, stream>>>(t1, W2, dis, hs2, n);
    aggF_k<<<NBKT, 256, 0, stream>>>(hs2, ebuf, bstart, dis, b2, h2, pbuf, n);

    bn_final_k<<<1, 256, 0, stream>>>(pbuf, gamma, beta, n, NBKT, bnscale, bnshift);
    bn_apply_k<<<(n * 16 + 255) / 256, 256, 0, stream>>>(h2, bnscale, bnshift, (float*)d_out, n);
}

// Round 10
// 238.933 us; speedup vs baseline: 6.3415x; 6.3415x over previous
//
#include <hip/hip_runtime.h>

// GCN 2-layer + BatchNorm1d forward.
// R10: revert R9's aggF (LDS f32 atomic scatter = 682us serialization disaster;
//      lesson: never convert a gather into an atomic scatter). Back to the
//      proven R8 pipeline; agg64 rebuilt as ONE WAVE PER NODE: 4 edge-groups
//      x 16 dim-lanes, stride-4 edge split, register partials, shfl_xor(16,32)
//      cross-group reduce. Kills the max-of-4-degrees wave imbalance
//      (21 -> deg/4 = 4 sequential gathers/wave) with zero atomics.
// Kept: layer-1 commute A(XW)=(AX)W (gathers on 64-dim fp16 rows, f32 accum),
//      counting-sort CSR (hist/scan_bucket/scan_total/scatB/buildC),
//      dot2 GEMMs, atomic-free BN.
// Pipeline: hist -> scan_bucket -> scan_total -> scatB -> buildC (CSR+dis)
//   -> prescale es=fp16(dis*emb) -> agg64 ag1 -> gemmA t1 -> gemmB hs2
//   -> agg64 h2 -> bn_part -> bn_final -> bn_apply -> d_out f32.

#define EPS_BN 1e-5f
#define NBKT_PAD 1024   // >= ceil(N/128); N=100000 -> 782 buckets
#define BN_NB 128       // bn_part blocks (partial-sum slots)
#define SCAT_B 256      // edge-pass blocks (1024 threads each)

typedef _Float16 f16;
typedef _Float16 f16x2 __attribute__((ext_vector_type(2)));
union pk4 { ushort4 u; f16 h[4]; f16x2 h2[2]; };

#if __has_builtin(__builtin_amdgcn_fdot2)
__device__ __forceinline__ float fdot2(f16x2 a, f16x2 b, float c) {
    return __builtin_amdgcn_fdot2(a, b, c, false);
}
#else
__device__ __forceinline__ float fdot2(f16x2 a, f16x2 b, float c) {
    return c + (float)a[0] * (float)b[0] + (float)a[1] * (float)b[1];
}
#endif

// ---------------- hist: per-block bucket histogram -> ghist ----------------
__global__ __launch_bounds__(1024) void hist_k(const int* __restrict__ colv, int E, int epb,
                                               int* __restrict__ ghist) {
    __shared__ int bins[NBKT_PAD];
    int tid = threadIdx.x;
    bins[tid] = 0;
    __syncthreads();
    int e0 = blockIdx.x * epb;
    int e1 = min(E, e0 + epb);
    for (int e = e0 + tid; e < e1; e += 1024)
        atomicAdd(&bins[colv[e] >> 7], 1);
    __syncthreads();
    ghist[blockIdx.x * NBKT_PAD + tid] = bins[tid];
}

// ---------------- scan_bucket: per-bucket exclusive prefix over the 256 blocks ----------------
__global__ __launch_bounds__(256) void scan_bucket_k(int* __restrict__ ghist, int* __restrict__ bcnt) {
    __shared__ int s[256];
    int k = blockIdx.x;
    int b = threadIdx.x;
    int v = ghist[b * NBKT_PAD + k];
    s[b] = v; __syncthreads();
    for (int off = 1; off < 256; off <<= 1) {
        int t = (b >= off) ? s[b - off] : 0;
        __syncthreads();
        s[b] += t;
        __syncthreads();
    }
    ghist[b * NBKT_PAD + k] = s[b] - v;           // exclusive within bucket
    if (b == 255) bcnt[k] = s[255];
}

// ---------------- scan_total: exclusive scan of bucket totals ----------------
__global__ __launch_bounds__(1024) void scan_total_k(const int* __restrict__ bcnt,
                                                     int* __restrict__ bstart,
                                                     int* __restrict__ start, int n, int E) {
    __shared__ int s[1024];
    int tid = threadIdx.x;
    int v = bcnt[tid];
    s[tid] = v; __syncthreads();
    for (int off = 1; off < 1024; off <<= 1) {
        int t = (tid >= off) ? s[tid - off] : 0;
        __syncthreads();
        s[tid] += t;
        __syncthreads();
    }
    bstart[tid] = s[tid] - v;
    if (tid == 1023) bstart[1024] = s[1023];
    if (tid == 0) start[n] = E;
}

// ---------------- scatB: single-pass scatter (cursor = ghist + bstart) ----------------
__global__ __launch_bounds__(1024) void scatB_k(const int* __restrict__ rowv, const int* __restrict__ colv,
                                                int E, int epb, const int* __restrict__ ghist,
                                                const int* __restrict__ bstart,
                                                unsigned* __restrict__ ebuf) {
    __shared__ int bins[NBKT_PAD];
    int tid = threadIdx.x;
    bins[tid] = ghist[blockIdx.x * NBKT_PAD + tid] + bstart[tid];
    __syncthreads();
    int e0 = blockIdx.x * epb;
    int e1 = min(E, e0 + epb);
    for (int e = e0 + tid; e < e1; e += 1024) {
        int c = colv[e];
        int p = atomicAdd(&bins[c >> 7], 1);
        ebuf[p] = ((unsigned)rowv[e] << 7) | (unsigned)(c & 127);
    }
}

// ---------------- buildC: per-bucket CSR finalize ----------------
__global__ __launch_bounds__(512) void buildC_k(const unsigned* __restrict__ ebuf,
                                                const int* __restrict__ bstart,
                                                int* __restrict__ start, int* __restrict__ srcs,
                                                float* __restrict__ dis, int n) {
    __shared__ int ncnt[128], noff[128], stmp[128];
    int b = blockIdx.x;
    int tid = threadIdx.x;
    int e0 = bstart[b], e1 = bstart[b + 1];
    if (tid < 128) ncnt[tid] = 0;
    __syncthreads();
    for (int e = e0 + tid; e < e1; e += 512)
        atomicAdd(&ncnt[ebuf[e] & 127u], 1);
    __syncthreads();
    if (tid < 128) stmp[tid] = ncnt[tid];
    __syncthreads();
    for (int off = 1; off < 128; off <<= 1) {
        int t = (tid < 128 && tid >= off) ? stmp[tid - off] : 0;
        __syncthreads();
        if (tid < 128) stmp[tid] += t;
        __syncthreads();
    }
    if (tid < 128) {
        int excl = stmp[tid] - ncnt[tid];
        noff[tid] = e0 + excl;
        int node = b * 128 + tid;
        if (node < n) {
            start[node] = e0 + excl;
            dis[node] = rsqrtf((float)(ncnt[tid] + 1));   // +1 self-loop
        }
    }
    __syncthreads();
    for (int e = e0 + tid; e < e1; e += 512) {
        unsigned p = ebuf[e];
        int pos = atomicAdd(&noff[p & 127u], 1);
        srcs[pos] = (int)(p >> 7);
    }
}

// ---------------- prescale: es = fp16(dis * emb), 64-dim ----------------
__global__ __launch_bounds__(256) void prescale_k(const float* __restrict__ emb,
                                                  const float* __restrict__ dis,
                                                  f16* __restrict__ es, int n) {
    int gid = blockIdx.x * 256 + threadIdx.x;
    int node = gid >> 4, q = gid & 15;
    if (node >= n) return;
    float d = dis[node];
    float4 v = ((const float4*)emb)[(size_t)node * 16 + q];
    pk4 p;
    p.h[0] = (f16)(v.x * d); p.h[1] = (f16)(v.y * d);
    p.h[2] = (f16)(v.z * d); p.h[3] = (f16)(v.w * d);
    ((ushort4*)es)[(size_t)node * 16 + q] = p.u;
}

__device__ __forceinline__ void acc_pk(float4& acc, ushort4 u) {
    pk4 p; p.u = u;
    acc.x += (float)p.h[0]; acc.y += (float)p.h[1];
    acc.z += (float)p.h[2]; acc.w += (float)p.h[3];
}

// ---------------- agg64: ONE WAVE PER NODE (4 edge-groups x 16 dim-lanes) ----------------
// out = fp16(dis[node]*(table[node] + Σ_src table[src]) + bias); pure gather, no atomics.
__global__ __launch_bounds__(256) void agg64_k(const f16* __restrict__ table, const int* __restrict__ start,
                                               const int* __restrict__ srcs, const float* __restrict__ dis,
                                               const float* __restrict__ bias, f16* __restrict__ out, int n) {
    int node = (blockIdx.x * 256 + threadIdx.x) >> 6;
    if (node >= n) return;
    int lane = threadIdx.x & 63;
    int q = lane & 15, g = lane >> 4;             // dim-quad, edge-group
    const ushort4* t4 = (const ushort4*)table;
    float4 acc = make_float4(0.f, 0.f, 0.f, 0.f);
    if (g == 0) acc_pk(acc, t4[(size_t)node * 16 + q]);   // self-loop (once)
    int s0 = start[node], s1 = start[node + 1];
    int e = s0 + g;
    for (; e + 12 < s1; e += 16) {                // 4-deep MLP per group
        int i0 = srcs[e], i1 = srcs[e + 4], i2 = srcs[e + 8], i3 = srcs[e + 12];
        ushort4 v0 = t4[(size_t)i0 * 16 + q];
        ushort4 v1 = t4[(size_t)i1 * 16 + q];
        ushort4 v2 = t4[(size_t)i2 * 16 + q];
        ushort4 v3 = t4[(size_t)i3 * 16 + q];
        acc_pk(acc, v0); acc_pk(acc, v1); acc_pk(acc, v2); acc_pk(acc, v3);
    }
    for (; e < s1; e += 4) acc_pk(acc, t4[(size_t)srcs[e] * 16 + q]);
    // cross-group reduce: lanes ^16 then ^32
    acc.x += __shfl_xor(acc.x, 16, 64); acc.y += __shfl_xor(acc.y, 16, 64);
    acc.z += __shfl_xor(acc.z, 16, 64); acc.w += __shfl_xor(acc.w, 16, 64);
    acc.x += __shfl_xor(acc.x, 32, 64); acc.y += __shfl_xor(acc.y, 32, 64);
    acc.z += __shfl_xor(acc.z, 32, 64); acc.w += __shfl_xor(acc.w, 32, 64);
    if (g == 0) {
        float d = dis[node];
        float4 b = make_float4(0.f, 0.f, 0.f, 0.f);
        if (bias) b = ((const float4*)bias)[q];
        pk4 p;
        p.h[0] = (f16)(acc.x * d + b.x); p.h[1] = (f16)(acc.y * d + b.y);
        p.h[2] = (f16)(acc.z * d + b.z); p.h[3] = (f16)(acc.w * d + b.w);
        ((ushort4*)out)[(size_t)node * 16 + q] = p.u;
    }
}

// ---------------- gemmA: t1 = fp16(ag1[n,64] @ W1[64,128] + b1) ----------------
__global__ __launch_bounds__(256) void gemmA_k(const f16* __restrict__ ag1, const float* __restrict__ W1,
                                               const float* __restrict__ b1, f16* __restrict__ t1, int n) {
    __shared__ f16x2 sW[32 * 128];    // [kk][c] = (W1[2kk][c], W1[2kk+1][c])
    __shared__ f16x2 sA[32 * 34];     // [r][kk], padded
    int tid = threadIdx.x;
    for (int i = tid; i < 32 * 128; i += 256) {
        int kk = i >> 7, c = i & 127;
        f16x2 w; w[0] = (f16)W1[(2 * kk) * 128 + c]; w[1] = (f16)W1[(2 * kk + 1) * 128 + c];
        sW[i] = w;
    }
    int rowbase = blockIdx.x * 32;
    for (int i = tid; i < 512; i += 256) {            // 32 rows x 16 ushort4
        int r = i >> 4, q = i & 15;
        int gr = rowbase + r;
        ushort4 u = make_ushort4(0, 0, 0, 0);
        if (gr < n) u = ((const ushort4*)ag1)[(size_t)gr * 16 + q];
        ((ushort4*)sA)[r * 17 + q] = u;
    }
    __syncthreads();
    int L = tid & 31, rg = tid >> 5;                  // cols 4L..4L+3, rows rg*4..+3
    float acc[4][4] = {};
#pragma unroll 4
    for (int kk = 0; kk < 32; kk++) {
        f16x2 w0 = sW[kk * 128 + 4 * L];
        f16x2 w1 = sW[kk * 128 + 4 * L + 1];
        f16x2 w2 = sW[kk * 128 + 4 * L + 2];
        f16x2 w3 = sW[kk * 128 + 4 * L + 3];
#pragma unroll
        for (int rr = 0; rr < 4; rr++) {
            f16x2 a = sA[(rg * 4 + rr) * 34 + kk];
            acc[rr][0] = fdot2(a, w0, acc[rr][0]);
            acc[rr][1] = fdot2(a, w1, acc[rr][1]);
            acc[rr][2] = fdot2(a, w2, acc[rr][2]);
            acc[rr][3] = fdot2(a, w3, acc[rr][3]);
        }
    }
    float4 bb = *(const float4*)(b1 + 4 * L);
#pragma unroll
    for (int rr = 0; rr < 4; rr++) {
        int row = rowbase + rg * 4 + rr;
        if (row < n) {
            pk4 p;
            p.h[0] = (f16)(acc[rr][0] + bb.x); p.h[1] = (f16)(acc[rr][1] + bb.y);
            p.h[2] = (f16)(acc[rr][2] + bb.z); p.h[3] = (f16)(acc[rr][3] + bb.w);
            ((ushort4*)t1)[(size_t)row * 32 + L] = p.u;
        }
    }
}

// ---------------- gemmB: hs2 = fp16(dis * (t1[n,128] @ W2[128,64])) ----------------
__global__ __launch_bounds__(256) void gemmB_k(const f16* __restrict__ t1, const float* __restrict__ W2,
                                               const float* __restrict__ dis, f16* __restrict__ hs2, int n) {
    __shared__ f16x2 sW[64 * 64];     // [kk][c] = (W2[2kk][c], W2[2kk+1][c])
    __shared__ f16x2 sA[64 * 66];     // [r][kk], padded (+2)
    int tid = threadIdx.x;
    for (int i = tid; i < 64 * 64; i += 256) {
        int kk = i >> 6, c = i & 63;
        f16x2 w; w[0] = (f16)W2[(2 * kk) * 64 + c]; w[1] = (f16)W2[(2 * kk + 1) * 64 + c];
        sW[i] = w;
    }
    int rowbase = blockIdx.x * 64;
    for (int i = tid; i < 2048; i += 256) {           // 64 rows x 32 ushort4
        int r = i >> 5, q = i & 31;
        int gr = rowbase + r;
        ushort4 u = make_ushort4(0, 0, 0, 0);
        if (gr < n) u = ((const ushort4*)t1)[(size_t)gr * 32 + q];
        ((ushort4*)sA)[r * 33 + q] = u;
    }
    __syncthreads();
    int L = tid & 15, rg = tid >> 4;                  // cols 4L..4L+3, rows rg*4..+3
    float acc[4][4] = {};
#pragma unroll 4
    for (int kk = 0; kk < 64; kk++) {
        f16x2 w0 = sW[kk * 64 + 4 * L];
        f16x2 w1 = sW[kk * 64 + 4 * L + 1];
        f16x2 w2 = sW[kk * 64 + 4 * L + 2];
        f16x2 w3 = sW[kk * 64 + 4 * L + 3];
#pragma unroll
        for (int rr = 0; rr < 4; rr++) {
            f16x2 a = sA[(rg * 4 + rr) * 66 + kk];
            acc[rr][0] = fdot2(a, w0, acc[rr][0]);
            acc[rr][1] = fdot2(a, w1, acc[rr][1]);
            acc[rr][2] = fdot2(a, w2, acc[rr][2]);
            acc[rr][3] = fdot2(a, w3, acc[rr][3]);
        }
    }
#pragma unroll
    for (int rr = 0; rr < 4; rr++) {
        int row = rowbase + rg * 4 + rr;
        if (row < n) {
            float d = dis[row];
            pk4 p;
            p.h[0] = (f16)(acc[rr][0] * d); p.h[1] = (f16)(acc[rr][1] * d);
            p.h[2] = (f16)(acc[rr][2] * d); p.h[3] = (f16)(acc[rr][3] * d);
            ((ushort4*)hs2)[(size_t)row * 16 + L] = p.u;
        }
    }
}

// ---------------- batchnorm: per-block partials, NO global atomics ----------------
__global__ __launch_bounds__(256) void bn_part_k(const f16* __restrict__ x, float* __restrict__ pbuf, int n) {
    __shared__ float4 ls[256], lq[256];
    int q = threadIdx.x & 15;     // cols 4q..4q+3
    int rg = threadIdx.x >> 4;    // 0..15
    float4 s = make_float4(0.f, 0.f, 0.f, 0.f);
    float4 ss = make_float4(0.f, 0.f, 0.f, 0.f);
    for (int row = blockIdx.x * 16 + rg; row < n; row += gridDim.x * 16) {
        pk4 p; p.u = ((const ushort4*)x)[(size_t)row * 16 + q];
        float v0 = p.h[0], v1 = p.h[1], v2 = p.h[2], v3 = p.h[3];
        s.x += v0; s.y += v1; s.z += v2; s.w += v3;
        ss.x += v0 * v0; ss.y += v1 * v1; ss.z += v2 * v2; ss.w += v3 * v3;
    }
    ls[threadIdx.x] = s; lq[threadIdx.x] = ss;
    __syncthreads();
    if (threadIdx.x < 16) {
        float4 S = make_float4(0.f, 0.f, 0.f, 0.f);
        float4 Q = make_float4(0.f, 0.f, 0.f, 0.f);
        for (int g = 0; g < 16; g++) {
            float4 a = ls[g * 16 + threadIdx.x], b = lq[g * 16 + threadIdx.x];
            S.x += a.x; S.y += a.y; S.z += a.z; S.w += a.w;
            Q.x += b.x; Q.y += b.y; Q.z += b.z; Q.w += b.w;
        }
        float4* dst = (float4*)(pbuf + (size_t)blockIdx.x * 128);
        dst[threadIdx.x] = S;
        dst[threadIdx.x + 16] = Q;
    }
}

__global__ __launch_bounds__(64) void bn_final_k(const float* __restrict__ pbuf,
                                                 const float* __restrict__ gamma, const float* __restrict__ beta,
                                                 int n, float* __restrict__ scale, float* __restrict__ shift) {
    int c = threadIdx.x;
    float s = 0.f, q = 0.f;
    for (int b = 0; b < BN_NB; b++) {
        s += pbuf[b * 128 + c];
        q += pbuf[b * 128 + 64 + c];
    }
    float inv_n = 1.f / (float)n;
    float mean = s * inv_n;
    float var = q * inv_n - mean * mean;          // biased variance
    float sc = gamma[c] * rsqrtf(var + EPS_BN);
    scale[c] = sc;
    shift[c] = beta[c] - mean * sc;
}

__global__ __launch_bounds__(256) void bn_apply_k(const f16* __restrict__ x, const float* __restrict__ scale,
                                                  const float* __restrict__ shift, float* __restrict__ out, int n) {
    __shared__ float sscale[64], sshift[64];
    if (threadIdx.x < 64) {
        sscale[threadIdx.x] = scale[threadIdx.x];
        sshift[threadIdx.x] = shift[threadIdx.x];
    }
    __syncthreads();
    int i = blockIdx.x * 256 + threadIdx.x;
    if (i < n * 16) {
        int c = (i & 15) * 4;
        pk4 p; p.u = ((const ushort4*)x)[i];
        float4 o;
        o.x = (float)p.h[0] * sscale[c]     + sshift[c];
        o.y = (float)p.h[1] * sscale[c + 1] + sshift[c + 1];
        o.z = (float)p.h[2] * sscale[c + 2] + sshift[c + 2];
        o.w = (float)p.h[3] * sscale[c + 3] + sshift[c + 3];
        ((float4*)out)[i] = o;
    }
}

extern "C" void kernel_launch(void* const* d_in, const int* in_sizes, int n_in,
                              void* d_out, int out_size, void* d_ws, size_t ws_size,
                              hipStream_t stream) {
    const float* emb   = (const float*)d_in[0];
    const float* W1    = (const float*)d_in[1];
    const float* b1    = (const float*)d_in[2];
    const float* W2    = (const float*)d_in[3];
    const float* b2    = (const float*)d_in[4];
    const float* gamma = (const float*)d_in[5];
    const float* beta  = (const float*)d_in[6];
    const int*   ei    = (const int*)d_in[7];     // [2,E] int32
    const int n = in_sizes[0] / 64;               // 100000
    const int E = in_sizes[7] / 2;                // 1600000
    const int* rowv = ei;                         // sources
    const int* colv = ei + E;                     // targets
    const int NBKT = (n + 127) / 128;             // 782

    char* ws = (char*)d_ws;
    size_t o = 0;
    auto alloc = [&](size_t bytes) -> char* {
        char* p = ws + o;
        o = (o + bytes + 255) & ~(size_t)255;
        return p;
    };
    int*   ghist   = (int*)alloc((size_t)SCAT_B * NBKT_PAD * 4);  // 1MB
    int*   bcnt    = (int*)alloc(NBKT_PAD * 4);
    int*   bstart  = (int*)alloc((NBKT_PAD + 1) * 4);
    int*   start   = (int*)alloc((size_t)(n + 1) * 4);
    float* dis     = (float*)alloc((size_t)n * 4);
    int*   srcs    = (int*)alloc((size_t)E * 4);
    float* pbuf    = (float*)alloc(BN_NB * 128 * 4);     // BN partials
    float* bnscale = (float*)alloc(256);
    float* bnshift = (float*)alloc(256);
    f16*   es      = (f16*)alloc((size_t)n * 64 * 2);    // dis*emb fp16
    f16*   ag1     = (f16*)alloc((size_t)n * 64 * 2);    // layer-1 aggregated
    f16*   t1      = (f16*)alloc((size_t)n * 128 * 2);   // h1 = ag1@W1+b1
    f16*   hs2     = (f16*)alloc((size_t)n * 64 * 2);    // dis*(t1@W2)
    f16*   h2      = (f16*)alloc((size_t)n * 64 * 2);    // pre-BN output
    unsigned* ebuf = (unsigned*)alloc((size_t)E * 4);    // packed bucket edges

    int epb = (E + SCAT_B - 1) / SCAT_B;          // 6250

    hist_k<<<SCAT_B, 1024, 0, stream>>>(colv, E, epb, ghist);
    scan_bucket_k<<<NBKT_PAD, 256, 0, stream>>>(ghist, bcnt);
    scan_total_k<<<1, 1024, 0, stream>>>(bcnt, bstart, start, n, E);
    scatB_k<<<SCAT_B, 1024, 0, stream>>>(rowv, colv, E, epb, ghist, bstart, ebuf);
    buildC_k<<<NBKT, 512, 0, stream>>>(ebuf, bstart, start, srcs, dis, n);

    prescale_k<<<(n * 16 + 255) / 256, 256, 0, stream>>>(emb, dis, es, n);
    agg64_k<<<(n + 3) / 4, 256, 0, stream>>>(es, start, srcs, dis, nullptr, ag1, n);
    gemmA_k<<<(n + 31) / 32, 256, 0, stream>>>(ag1, W1, b1, t1, n);
    gemmB_k<<<(n + 63) / 64, 256, 0, stream>>>(t1, W2, dis, hs2, n);
    agg64_k<<<(n + 3) / 4, 256, 0, stream>>>(hs2, start, srcs, dis, b2, h2, n);

    bn_part_k<<<BN_NB, 256, 0, stream>>>(h2, pbuf, n);
    bn_final_k<<<1, 64, 0, stream>>>(pbuf, gamma, beta, n, bnscale, bnshift);
    bn_apply_k<<<(n * 16 + 255) / 256, 256, 0, stream>>>(h2, bnscale, bnshift, (float*)d_out, n);
}

// Round 11
// 203.747 us; speedup vs baseline: 7.4366x; 1.1727x over previous
//
#include <hip/hip_runtime.h>

// GCN 2-layer + BatchNorm1d forward.
// R11: (1) agg64 reverted to R8's proven 16-lanes/node form (R10's one-wave-
//      per-node was 2x slower: 4-deep MLP only, redundant srcs broadcasts,
//      serial 8-step shfl chain amortized over ~16 edges). (2) gemmA+gemmB
//      fused (R4 idea, R5 discipline): h1 tile in padded LDS, bounded unroll,
//      two light phases -> saves the t1 25.6MB round-trip + one launch.
// Gather FETCH (~88MB) = unique-(XCD,line) floor N(1-e^-2)*128B*8; fill rate
// ceiling ~3.4 TB/s measured -> ~27us/gather is the floor for this graph.
// Pipeline: hist -> scan_bucket -> scan_total -> scatB -> buildC (CSR+dis)
//   -> prescale es=fp16(dis*emb) -> agg64 ag1 -> gemmAB hs2 -> agg64 h2
//   -> bn_part -> bn_final -> bn_apply -> d_out f32.

#define EPS_BN 1e-5f
#define NBKT_PAD 1024   // >= ceil(N/128); N=100000 -> 782 buckets
#define BN_NB 128       // bn_part blocks (partial-sum slots)
#define SCAT_B 256      // edge-pass blocks (1024 threads each)

typedef _Float16 f16;
typedef _Float16 f16x2 __attribute__((ext_vector_type(2)));
union pk4 { ushort4 u; f16 h[4]; f16x2 h2[2]; };

#if __has_builtin(__builtin_amdgcn_fdot2)
__device__ __forceinline__ float fdot2(f16x2 a, f16x2 b, float c) {
    return __builtin_amdgcn_fdot2(a, b, c, false);
}
#else
__device__ __forceinline__ float fdot2(f16x2 a, f16x2 b, float c) {
    return c + (float)a[0] * (float)b[0] + (float)a[1] * (float)b[1];
}
#endif

// ---------------- hist: per-block bucket histogram -> ghist ----------------
__global__ __launch_bounds__(1024) void hist_k(const int* __restrict__ colv, int E, int epb,
                                               int* __restrict__ ghist) {
    __shared__ int bins[NBKT_PAD];
    int tid = threadIdx.x;
    bins[tid] = 0;
    __syncthreads();
    int e0 = blockIdx.x * epb;
    int e1 = min(E, e0 + epb);
    for (int e = e0 + tid; e < e1; e += 1024)
        atomicAdd(&bins[colv[e] >> 7], 1);
    __syncthreads();
    ghist[blockIdx.x * NBKT_PAD + tid] = bins[tid];
}

// ---------------- scan_bucket: per-bucket exclusive prefix over the 256 blocks ----------------
__global__ __launch_bounds__(256) void scan_bucket_k(int* __restrict__ ghist, int* __restrict__ bcnt) {
    __shared__ int s[256];
    int k = blockIdx.x;
    int b = threadIdx.x;
    int v = ghist[b * NBKT_PAD + k];
    s[b] = v; __syncthreads();
    for (int off = 1; off < 256; off <<= 1) {
        int t = (b >= off) ? s[b - off] : 0;
        __syncthreads();
        s[b] += t;
        __syncthreads();
    }
    ghist[b * NBKT_PAD + k] = s[b] - v;           // exclusive within bucket
    if (b == 255) bcnt[k] = s[255];
}

// ---------------- scan_total: exclusive scan of bucket totals ----------------
__global__ __launch_bounds__(1024) void scan_total_k(const int* __restrict__ bcnt,
                                                     int* __restrict__ bstart,
                                                     int* __restrict__ start, int n, int E) {
    __shared__ int s[1024];
    int tid = threadIdx.x;
    int v = bcnt[tid];
    s[tid] = v; __syncthreads();
    for (int off = 1; off < 1024; off <<= 1) {
        int t = (tid >= off) ? s[tid - off] : 0;
        __syncthreads();
        s[tid] += t;
        __syncthreads();
    }
    bstart[tid] = s[tid] - v;
    if (tid == 1023) bstart[1024] = s[1023];
    if (tid == 0) start[n] = E;
}

// ---------------- scatB: single-pass scatter (cursor = ghist + bstart) ----------------
__global__ __launch_bounds__(1024) void scatB_k(const int* __restrict__ rowv, const int* __restrict__ colv,
                                                int E, int epb, const int* __restrict__ ghist,
                                                const int* __restrict__ bstart,
                                                unsigned* __restrict__ ebuf) {
    __shared__ int bins[NBKT_PAD];
    int tid = threadIdx.x;
    bins[tid] = ghist[blockIdx.x * NBKT_PAD + tid] + bstart[tid];
    __syncthreads();
    int e0 = blockIdx.x * epb;
    int e1 = min(E, e0 + epb);
    for (int e = e0 + tid; e < e1; e += 1024) {
        int c = colv[e];
        int p = atomicAdd(&bins[c >> 7], 1);
        ebuf[p] = ((unsigned)rowv[e] << 7) | (unsigned)(c & 127);
    }
}

// ---------------- buildC: per-bucket CSR finalize ----------------
__global__ __launch_bounds__(512) void buildC_k(const unsigned* __restrict__ ebuf,
                                                const int* __restrict__ bstart,
                                                int* __restrict__ start, int* __restrict__ srcs,
                                                float* __restrict__ dis, int n) {
    __shared__ int ncnt[128], noff[128], stmp[128];
    int b = blockIdx.x;
    int tid = threadIdx.x;
    int e0 = bstart[b], e1 = bstart[b + 1];
    if (tid < 128) ncnt[tid] = 0;
    __syncthreads();
    for (int e = e0 + tid; e < e1; e += 512)
        atomicAdd(&ncnt[ebuf[e] & 127u], 1);
    __syncthreads();
    if (tid < 128) stmp[tid] = ncnt[tid];
    __syncthreads();
    for (int off = 1; off < 128; off <<= 1) {
        int t = (tid < 128 && tid >= off) ? stmp[tid - off] : 0;
        __syncthreads();
        if (tid < 128) stmp[tid] += t;
        __syncthreads();
    }
    if (tid < 128) {
        int excl = stmp[tid] - ncnt[tid];
        noff[tid] = e0 + excl;
        int node = b * 128 + tid;
        if (node < n) {
            start[node] = e0 + excl;
            dis[node] = rsqrtf((float)(ncnt[tid] + 1));   // +1 self-loop
        }
    }
    __syncthreads();
    for (int e = e0 + tid; e < e1; e += 512) {
        unsigned p = ebuf[e];
        int pos = atomicAdd(&noff[p & 127u], 1);
        srcs[pos] = (int)(p >> 7);
    }
}

// ---------------- prescale: es = fp16(dis * emb), 64-dim ----------------
__global__ __launch_bounds__(256) void prescale_k(const float* __restrict__ emb,
                                                  const float* __restrict__ dis,
                                                  f16* __restrict__ es, int n) {
    int gid = blockIdx.x * 256 + threadIdx.x;
    int node = gid >> 4, q = gid & 15;
    if (node >= n) return;
    float d = dis[node];
    float4 v = ((const float4*)emb)[(size_t)node * 16 + q];
    pk4 p;
    p.h[0] = (f16)(v.x * d); p.h[1] = (f16)(v.y * d);
    p.h[2] = (f16)(v.z * d); p.h[3] = (f16)(v.w * d);
    ((ushort4*)es)[(size_t)node * 16 + q] = p.u;
}

__device__ __forceinline__ void acc_pk(float4& acc, ushort4 u) {
    pk4 p; p.u = u;
    acc.x += (float)p.h[0]; acc.y += (float)p.h[1];
    acc.z += (float)p.h[2]; acc.w += (float)p.h[3];
}

// ---------------- agg64 (R8 form): 16 lanes/node, 8-deep unroll, pure gather ----------------
__global__ __launch_bounds__(256) void agg64_k(const f16* __restrict__ table, const int* __restrict__ start,
                                               const int* __restrict__ srcs, const float* __restrict__ dis,
                                               const float* __restrict__ bias, f16* __restrict__ out, int n) {
    int node = blockIdx.x * 16 + (threadIdx.x >> 4);
    if (node >= n) return;
    int lane = threadIdx.x & 15;
    const ushort4* t4 = (const ushort4*)table;
    float4 acc = make_float4(0.f, 0.f, 0.f, 0.f);
    acc_pk(acc, t4[(size_t)node * 16 + lane]);            // self-loop term
    int s0 = start[node], s1 = start[node + 1];
    int e = s0;
    for (; e + 7 < s1; e += 8) {
        int i0 = srcs[e],     i1 = srcs[e + 1], i2 = srcs[e + 2], i3 = srcs[e + 3];
        int i4 = srcs[e + 4], i5 = srcs[e + 5], i6 = srcs[e + 6], i7 = srcs[e + 7];
        ushort4 v0 = t4[(size_t)i0 * 16 + lane];
        ushort4 v1 = t4[(size_t)i1 * 16 + lane];
        ushort4 v2 = t4[(size_t)i2 * 16 + lane];
        ushort4 v3 = t4[(size_t)i3 * 16 + lane];
        ushort4 v4 = t4[(size_t)i4 * 16 + lane];
        ushort4 v5 = t4[(size_t)i5 * 16 + lane];
        ushort4 v6 = t4[(size_t)i6 * 16 + lane];
        ushort4 v7 = t4[(size_t)i7 * 16 + lane];
        acc_pk(acc, v0); acc_pk(acc, v1); acc_pk(acc, v2); acc_pk(acc, v3);
        acc_pk(acc, v4); acc_pk(acc, v5); acc_pk(acc, v6); acc_pk(acc, v7);
    }
    for (; e + 3 < s1; e += 4) {
        int i0 = srcs[e], i1 = srcs[e + 1], i2 = srcs[e + 2], i3 = srcs[e + 3];
        ushort4 v0 = t4[(size_t)i0 * 16 + lane];
        ushort4 v1 = t4[(size_t)i1 * 16 + lane];
        ushort4 v2 = t4[(size_t)i2 * 16 + lane];
        ushort4 v3 = t4[(size_t)i3 * 16 + lane];
        acc_pk(acc, v0); acc_pk(acc, v1); acc_pk(acc, v2); acc_pk(acc, v3);
    }
    for (; e < s1; e++) acc_pk(acc, t4[(size_t)srcs[e] * 16 + lane]);
    float d = dis[node];
    float4 b = make_float4(0.f, 0.f, 0.f, 0.f);
    if (bias) b = ((const float4*)bias)[lane];
    pk4 p;
    p.h[0] = (f16)(acc.x * d + b.x); p.h[1] = (f16)(acc.y * d + b.y);
    p.h[2] = (f16)(acc.z * d + b.z); p.h[3] = (f16)(acc.w * d + b.w);
    ((ushort4*)out)[(size_t)node * 16 + lane] = p.u;
}

// ---------------- gemmAB: hs2 = fp16(dis * ((ag1@W1 + b1) @ W2)), h1 in LDS ----------------
// 256 thr, 32 rows/block. Phase1: 8 rowgroups x 4 rows, 32 L x 4 cols (acc 4x4).
// Phase2: 16 rowgroups x 2 rows, 16 L x 4 cols (acc 2x4). sH padded [32][65] pairs.
__global__ __launch_bounds__(256) void gemmAB_k(const f16* __restrict__ ag1, const float* __restrict__ W1,
                                                const float* __restrict__ b1, const float* __restrict__ W2,
                                                const float* __restrict__ dis, f16* __restrict__ hs2, int n) {
    __shared__ f16x2 sW1[32 * 128];   // [kk][c] = (W1[2kk][c], W1[2kk+1][c])  16KB
    __shared__ f16x2 sW2[64 * 64];    // [kk][c] = (W2[2kk][c], W2[2kk+1][c])  16KB
    __shared__ f16x2 sA[32 * 34];     // [r][kk] padded                        4.25KB
    __shared__ f16x2 sH[32 * 65];     // [r][j] = (h1[r][2j], h1[r][2j+1]) padded 8.1KB
    int tid = threadIdx.x;
    for (int i = tid; i < 32 * 128; i += 256) {
        int kk = i >> 7, c = i & 127;
        f16x2 w; w[0] = (f16)W1[(2 * kk) * 128 + c]; w[1] = (f16)W1[(2 * kk + 1) * 128 + c];
        sW1[i] = w;
    }
    for (int i = tid; i < 64 * 64; i += 256) {
        int kk = i >> 6, c = i & 63;
        f16x2 w; w[0] = (f16)W2[(2 * kk) * 64 + c]; w[1] = (f16)W2[(2 * kk + 1) * 64 + c];
        sW2[i] = w;
    }
    int rowbase = blockIdx.x * 32;
    for (int i = tid; i < 512; i += 256) {            // 32 rows x 16 ushort4
        int r = i >> 4, q = i & 15;
        int gr = rowbase + r;
        ushort4 u = make_ushort4(0, 0, 0, 0);
        if (gr < n) u = ((const ushort4*)ag1)[(size_t)gr * 16 + q];
        ((ushort4*)sA)[r * 17 + q] = u;
    }
    __syncthreads();
    {   // phase 1: h1 = ag1@W1 + b1 -> sH
        int L = tid & 31, rg = tid >> 5;              // cols 4L..4L+3, rows rg*4..+3
        float acc[4][4] = {};
#pragma unroll 4
        for (int kk = 0; kk < 32; kk++) {
            f16x2 w0 = sW1[kk * 128 + 4 * L];
            f16x2 w1 = sW1[kk * 128 + 4 * L + 1];
            f16x2 w2 = sW1[kk * 128 + 4 * L + 2];
            f16x2 w3 = sW1[kk * 128 + 4 * L + 3];
#pragma unroll
            for (int rr = 0; rr < 4; rr++) {
                f16x2 a = sA[(rg * 4 + rr) * 34 + kk];
                acc[rr][0] = fdot2(a, w0, acc[rr][0]);
                acc[rr][1] = fdot2(a, w1, acc[rr][1]);
                acc[rr][2] = fdot2(a, w2, acc[rr][2]);
                acc[rr][3] = fdot2(a, w3, acc[rr][3]);
            }
        }
        float4 bb = *(const float4*)(b1 + 4 * L);
#pragma unroll
        for (int rr = 0; rr < 4; rr++) {
            int r = rg * 4 + rr;
            f16x2 p01, p23;
            p01[0] = (f16)(acc[rr][0] + bb.x); p01[1] = (f16)(acc[rr][1] + bb.y);
            p23[0] = (f16)(acc[rr][2] + bb.z); p23[1] = (f16)(acc[rr][3] + bb.w);
            sH[r * 65 + 2 * L]     = p01;             // k-pair 2L = cols 4L,4L+1
            sH[r * 65 + 2 * L + 1] = p23;             // k-pair 2L+1 = cols 4L+2,4L+3
        }
    }
    __syncthreads();
    {   // phase 2: hs2 = dis * (h1 @ W2)
        int L = tid & 15, rg = tid >> 4;              // cols 4L..4L+3, rows rg*2..+1
        float acc[2][4] = {};
#pragma unroll 4
        for (int kk = 0; kk < 64; kk++) {
            f16x2 w0 = sW2[kk * 64 + 4 * L];
            f16x2 w1 = sW2[kk * 64 + 4 * L + 1];
            f16x2 w2 = sW2[kk * 64 + 4 * L + 2];
            f16x2 w3 = sW2[kk * 64 + 4 * L + 3];
#pragma unroll
            for (int rr = 0; rr < 2; rr++) {
                f16x2 a = sH[(rg * 2 + rr) * 65 + kk];
                acc[rr][0] = fdot2(a, w0, acc[rr][0]);
                acc[rr][1] = fdot2(a, w1, acc[rr][1]);
                acc[rr][2] = fdot2(a, w2, acc[rr][2]);
                acc[rr][3] = fdot2(a, w3, acc[rr][3]);
            }
        }
#pragma unroll
        for (int rr = 0; rr < 2; rr++) {
            int row = rowbase + rg * 2 + rr;
            if (row < n) {
                float d = dis[row];
                pk4 p;
                p.h[0] = (f16)(acc[rr][0] * d); p.h[1] = (f16)(acc[rr][1] * d);
                p.h[2] = (f16)(acc[rr][2] * d); p.h[3] = (f16)(acc[rr][3] * d);
                ((ushort4*)hs2)[(size_t)row * 16 + L] = p.u;
            }
        }
    }
}

// ---------------- batchnorm: per-block partials, NO global atomics ----------------
__global__ __launch_bounds__(256) void bn_part_k(const f16* __restrict__ x, float* __restrict__ pbuf, int n) {
    __shared__ float4 ls[256], lq[256];
    int q = threadIdx.x & 15;     // cols 4q..4q+3
    int rg = threadIdx.x >> 4;    // 0..15
    float4 s = make_float4(0.f, 0.f, 0.f, 0.f);
    float4 ss = make_float4(0.f, 0.f, 0.f, 0.f);
    for (int row = blockIdx.x * 16 + rg; row < n; row += gridDim.x * 16) {
        pk4 p; p.u = ((const ushort4*)x)[(size_t)row * 16 + q];
        float v0 = p.h[0], v1 = p.h[1], v2 = p.h[2], v3 = p.h[3];
        s.x += v0; s.y += v1; s.z += v2; s.w += v3;
        ss.x += v0 * v0; ss.y += v1 * v1; ss.z += v2 * v2; ss.w += v3 * v3;
    }
    ls[threadIdx.x] = s; lq[threadIdx.x] = ss;
    __syncthreads();
    if (threadIdx.x < 16) {
        float4 S = make_float4(0.f, 0.f, 0.f, 0.f);
        float4 Q = make_float4(0.f, 0.f, 0.f, 0.f);
        for (int g = 0; g < 16; g++) {
            float4 a = ls[g * 16 + threadIdx.x], b = lq[g * 16 + threadIdx.x];
            S.x += a.x; S.y += a.y; S.z += a.z; S.w += a.w;
            Q.x += b.x; Q.y += b.y; Q.z += b.z; Q.w += b.w;
        }
        float4* dst = (float4*)(pbuf + (size_t)blockIdx.x * 128);
        dst[threadIdx.x] = S;
        dst[threadIdx.x + 16] = Q;
    }
}

__global__ __launch_bounds__(64) void bn_final_k(const float* __restrict__ pbuf,
                                                 const float* __restrict__ gamma, const float* __restrict__ beta,
                                                 int n, float* __restrict__ scale, float* __restrict__ shift) {
    int c = threadIdx.x;
    float s = 0.f, q = 0.f;
    for (int b = 0; b < BN_NB; b++) {
        s += pbuf[b * 128 + c];
        q += pbuf[b * 128 + 64 + c];
    }
    float inv_n = 1.f / (float)n;
    float mean = s * inv_n;
    float var = q * inv_n - mean * mean;          // biased variance
    float sc = gamma[c] * rsqrtf(var + EPS_BN);
    scale[c] = sc;
    shift[c] = beta[c] - mean * sc;
}

__global__ __launch_bounds__(256) void bn_apply_k(const f16* __restrict__ x, const float* __restrict__ scale,
                                                  const float* __restrict__ shift, float* __restrict__ out, int n) {
    __shared__ float sscale[64], sshift[64];
    if (threadIdx.x < 64) {
        sscale[threadIdx.x] = scale[threadIdx.x];
        sshift[threadIdx.x] = shift[threadIdx.x];
    }
    __syncthreads();
    int i = blockIdx.x * 256 + threadIdx.x;
    if (i < n * 16) {
        int c = (i & 15) * 4;
        pk4 p; p.u = ((const ushort4*)x)[i];
        float4 o;
        o.x = (float)p.h[0] * sscale[c]     + sshift[c];
        o.y = (float)p.h[1] * sscale[c + 1] + sshift[c + 1];
        o.z = (float)p.h[2] * sscale[c + 2] + sshift[c + 2];
        o.w = (float)p.h[3] * sscale[c + 3] + sshift[c + 3];
        ((float4*)out)[i] = o;
    }
}

extern "C" void kernel_launch(void* const* d_in, const int* in_sizes, int n_in,
                              void* d_out, int out_size, void* d_ws, size_t ws_size,
                              hipStream_t stream) {
    const float* emb   = (const float*)d_in[0];
    const float* W1    = (const float*)d_in[1];
    const float* b1    = (const float*)d_in[2];
    const float* W2    = (const float*)d_in[3];
    const float* b2    = (const float*)d_in[4];
    const float* gamma = (const float*)d_in[5];
    const float* beta  = (const float*)d_in[6];
    const int*   ei    = (const int*)d_in[7];     // [2,E] int32
    const int n = in_sizes[0] / 64;               // 100000
    const int E = in_sizes[7] / 2;                // 1600000
    const int* rowv = ei;                         // sources
    const int* colv = ei + E;                     // targets
    const int NBKT = (n + 127) / 128;             // 782

    char* ws = (char*)d_ws;
    size_t o = 0;
    auto alloc = [&](size_t bytes) -> char* {
        char* p = ws + o;
        o = (o + bytes + 255) & ~(size_t)255;
        return p;
    };
    int*   ghist   = (int*)alloc((size_t)SCAT_B * NBKT_PAD * 4);  // 1MB
    int*   bcnt    = (int*)alloc(NBKT_PAD * 4);
    int*   bstart  = (int*)alloc((NBKT_PAD + 1) * 4);
    int*   start   = (int*)alloc((size_t)(n + 1) * 4);
    float* dis     = (float*)alloc((size_t)n * 4);
    int*   srcs    = (int*)alloc((size_t)E * 4);
    float* pbuf    = (float*)alloc(BN_NB * 128 * 4);     // BN partials
    float* bnscale = (float*)alloc(256);
    float* bnshift = (float*)alloc(256);
    f16*   es      = (f16*)alloc((size_t)n * 64 * 2);    // dis*emb fp16
    f16*   ag1     = (f16*)alloc((size_t)n * 64 * 2);    // layer-1 aggregated
    f16*   hs2     = (f16*)alloc((size_t)n * 64 * 2);    // dis*((ag1@W1+b1)@W2)
    f16*   h2      = (f16*)alloc((size_t)n * 64 * 2);    // pre-BN output
    unsigned* ebuf = (unsigned*)alloc((size_t)E * 4);    // packed bucket edges

    int epb = (E + SCAT_B - 1) / SCAT_B;          // 6250

    hist_k<<<SCAT_B, 1024, 0, stream>>>(colv, E, epb, ghist);
    scan_bucket_k<<<NBKT_PAD, 256, 0, stream>>>(ghist, bcnt);
    scan_total_k<<<1, 1024, 0, stream>>>(bcnt, bstart, start, n, E);
    scatB_k<<<SCAT_B, 1024, 0, stream>>>(rowv, colv, E, epb, ghist, bstart, ebuf);
    buildC_k<<<NBKT, 512, 0, stream>>>(ebuf, bstart, start, srcs, dis, n);

    prescale_k<<<(n * 16 + 255) / 256, 256, 0, stream>>>(emb, dis, es, n);
    agg64_k<<<(n + 15) / 16, 256, 0, stream>>>(es, start, srcs, dis, nullptr, ag1, n);
    gemmAB_k<<<(n + 31) / 32, 256, 0, stream>>>(ag1, W1, b1, W2, dis, hs2, n);
    agg64_k<<<(n + 15) / 16, 256, 0, stream>>>(hs2, start, srcs, dis, b2, h2, n);

    bn_part_k<<<BN_NB, 256, 0, stream>>>(h2, pbuf, n);
    bn_final_k<<<1, 64, 0, stream>>>(pbuf, gamma, beta, n, bnscale, bnshift);
    bn_apply_k<<<(n * 16 + 255) / 256, 256, 0, stream>>>(h2, bnscale, bnshift, (float*)d_out, n);
}

// Round 12
// 179.838 us; speedup vs baseline: 8.4253x; 1.1329x over previous
//
#include <hip/hip_runtime.h>

// GCN 2-layer + BatchNorm1d forward.
// R12: GEMM pair moved to MFMA (v_mfma_f32_16x16x32_f16, f32 accum). R11
//      showed the dot2 form is instruction-issue bound at ~65-69us (819M
//      dot2 + 410M ds_read wave-ops); MFMA needs 32x fewer instructions
//      (~200K total = ~0.4us of matrix pipe). wprep pre-transposes weights
//      (w1t[n][k], w2t[n][k] f16) so A and B fragments are both contiguous
//      8xf16 loads (verified gfx950 layout: A lane l = row l&15,
//      k (l>>4)*8..+7; C/D col=l&15, row=(l>>4)*4+reg). A-frags direct from
//      global (each row read once); B-frags L1-hot; H1 staged in padded LDS
//      (only 17.4KB -> high occupancy).
// Kept: counting-sort CSR, R8-form agg64 gathers (FETCH = 86MB unique-line
//      floor, ~3.4TB/s fill ceiling -> ~27us each is the floor), fp16
//      tables, atomic-free BN.
// Pipeline: hist -> scan_bucket -> scan_total -> scatB -> buildC (CSR+dis)
//   -> wprep -> prescale es -> agg64 ag1 -> gemmAB_mfma hs2 -> agg64 h2
//   -> bn_part -> bn_final -> bn_apply -> d_out f32.

#define EPS_BN 1e-5f
#define NBKT_PAD 1024   // >= ceil(N/128); N=100000 -> 782 buckets
#define BN_NB 128       // bn_part blocks (partial-sum slots)
#define SCAT_B 256      // edge-pass blocks (1024 threads each)

typedef _Float16 f16;
typedef _Float16 f16x2 __attribute__((ext_vector_type(2)));
typedef _Float16 f16x8 __attribute__((ext_vector_type(8)));
typedef float f32x4 __attribute__((ext_vector_type(4)));
union pk4 { ushort4 u; f16 h[4]; f16x2 h2[2]; };

// ---------------- hist: per-block bucket histogram -> ghist ----------------
__global__ __launch_bounds__(1024) void hist_k(const int* __restrict__ colv, int E, int epb,
                                               int* __restrict__ ghist) {
    __shared__ int bins[NBKT_PAD];
    int tid = threadIdx.x;
    bins[tid] = 0;
    __syncthreads();
    int e0 = blockIdx.x * epb;
    int e1 = min(E, e0 + epb);
    for (int e = e0 + tid; e < e1; e += 1024)
        atomicAdd(&bins[colv[e] >> 7], 1);
    __syncthreads();
    ghist[blockIdx.x * NBKT_PAD + tid] = bins[tid];
}

// ---------------- scan_bucket: per-bucket exclusive prefix over the 256 blocks ----------------
__global__ __launch_bounds__(256) void scan_bucket_k(int* __restrict__ ghist, int* __restrict__ bcnt) {
    __shared__ int s[256];
    int k = blockIdx.x;
    int b = threadIdx.x;
    int v = ghist[b * NBKT_PAD + k];
    s[b] = v; __syncthreads();
    for (int off = 1; off < 256; off <<= 1) {
        int t = (b >= off) ? s[b - off] : 0;
        __syncthreads();
        s[b] += t;
        __syncthreads();
    }
    ghist[b * NBKT_PAD + k] = s[b] - v;           // exclusive within bucket
    if (b == 255) bcnt[k] = s[255];
}

// ---------------- scan_total: exclusive scan of bucket totals ----------------
__global__ __launch_bounds__(1024) void scan_total_k(const int* __restrict__ bcnt,
                                                     int* __restrict__ bstart,
                                                     int* __restrict__ start, int n, int E) {
    __shared__ int s[1024];
    int tid = threadIdx.x;
    int v = bcnt[tid];
    s[tid] = v; __syncthreads();
    for (int off = 1; off < 1024; off <<= 1) {
        int t = (tid >= off) ? s[tid - off] : 0;
        __syncthreads();
        s[tid] += t;
        __syncthreads();
    }
    bstart[tid] = s[tid] - v;
    if (tid == 1023) bstart[1024] = s[1023];
    if (tid == 0) start[n] = E;
}

// ---------------- scatB: single-pass scatter (cursor = ghist + bstart) ----------------
__global__ __launch_bounds__(1024) void scatB_k(const int* __restrict__ rowv, const int* __restrict__ colv,
                                                int E, int epb, const int* __restrict__ ghist,
                                                const int* __restrict__ bstart,
                                                unsigned* __restrict__ ebuf) {
    __shared__ int bins[NBKT_PAD];
    int tid = threadIdx.x;
    bins[tid] = ghist[blockIdx.x * NBKT_PAD + tid] + bstart[tid];
    __syncthreads();
    int e0 = blockIdx.x * epb;
    int e1 = min(E, e0 + epb);
    for (int e = e0 + tid; e < e1; e += 1024) {
        int c = colv[e];
        int p = atomicAdd(&bins[c >> 7], 1);
        ebuf[p] = ((unsigned)rowv[e] << 7) | (unsigned)(c & 127);
    }
}

// ---------------- buildC: per-bucket CSR finalize ----------------
__global__ __launch_bounds__(512) void buildC_k(const unsigned* __restrict__ ebuf,
                                                const int* __restrict__ bstart,
                                                int* __restrict__ start, int* __restrict__ srcs,
                                                float* __restrict__ dis, int n) {
    __shared__ int ncnt[128], noff[128], stmp[128];
    int b = blockIdx.x;
    int tid = threadIdx.x;
    int e0 = bstart[b], e1 = bstart[b + 1];
    if (tid < 128) ncnt[tid] = 0;
    __syncthreads();
    for (int e = e0 + tid; e < e1; e += 512)
        atomicAdd(&ncnt[ebuf[e] & 127u], 1);
    __syncthreads();
    if (tid < 128) stmp[tid] = ncnt[tid];
    __syncthreads();
    for (int off = 1; off < 128; off <<= 1) {
        int t = (tid < 128 && tid >= off) ? stmp[tid - off] : 0;
        __syncthreads();
        if (tid < 128) stmp[tid] += t;
        __syncthreads();
    }
    if (tid < 128) {
        int excl = stmp[tid] - ncnt[tid];
        noff[tid] = e0 + excl;
        int node = b * 128 + tid;
        if (node < n) {
            start[node] = e0 + excl;
            dis[node] = rsqrtf((float)(ncnt[tid] + 1));   // +1 self-loop
        }
    }
    __syncthreads();
    for (int e = e0 + tid; e < e1; e += 512) {
        unsigned p = ebuf[e];
        int pos = atomicAdd(&noff[p & 127u], 1);
        srcs[pos] = (int)(p >> 7);
    }
}

// ---------------- wprep: transpose+convert weights to f16 [n][k] ----------------
__global__ __launch_bounds__(256) void wprep_k(const float* __restrict__ W1, const float* __restrict__ W2,
                                               f16* __restrict__ w1t, f16* __restrict__ w2t) {
    int t = blockIdx.x * 256 + threadIdx.x;
    if (t < 8192) {                                // W1 [64][128] -> w1t [128][64]
        int k = t >> 7, c = t & 127;
        w1t[c * 64 + k] = (f16)W1[t];
    } else if (t < 16384) {                        // W2 [128][64] -> w2t [64][128]
        int i = t - 8192;
        int k = i >> 6, c = i & 63;
        w2t[c * 128 + k] = (f16)W2[i];
    }
}

// ---------------- prescale: es = fp16(dis * emb), 64-dim ----------------
__global__ __launch_bounds__(256) void prescale_k(const float* __restrict__ emb,
                                                  const float* __restrict__ dis,
                                                  f16* __restrict__ es, int n) {
    int gid = blockIdx.x * 256 + threadIdx.x;
    int node = gid >> 4, q = gid & 15;
    if (node >= n) return;
    float d = dis[node];
    float4 v = ((const float4*)emb)[(size_t)node * 16 + q];
    pk4 p;
    p.h[0] = (f16)(v.x * d); p.h[1] = (f16)(v.y * d);
    p.h[2] = (f16)(v.z * d); p.h[3] = (f16)(v.w * d);
    ((ushort4*)es)[(size_t)node * 16 + q] = p.u;
}

__device__ __forceinline__ void acc_pk(float4& acc, ushort4 u) {
    pk4 p; p.u = u;
    acc.x += (float)p.h[0]; acc.y += (float)p.h[1];
    acc.z += (float)p.h[2]; acc.w += (float)p.h[3];
}

// ---------------- agg64 (R8 form): 16 lanes/node, 8-deep unroll, pure gather ----------------
__global__ __launch_bounds__(256) void agg64_k(const f16* __restrict__ table, const int* __restrict__ start,
                                               const int* __restrict__ srcs, const float* __restrict__ dis,
                                               const float* __restrict__ bias, f16* __restrict__ out, int n) {
    int node = blockIdx.x * 16 + (threadIdx.x >> 4);
    if (node >= n) return;
    int lane = threadIdx.x & 15;
    const ushort4* t4 = (const ushort4*)table;
    float4 acc = make_float4(0.f, 0.f, 0.f, 0.f);
    acc_pk(acc, t4[(size_t)node * 16 + lane]);            // self-loop term
    int s0 = start[node], s1 = start[node + 1];
    int e = s0;
    for (; e + 7 < s1; e += 8) {
        int i0 = srcs[e],     i1 = srcs[e + 1], i2 = srcs[e + 2], i3 = srcs[e + 3];
        int i4 = srcs[e + 4], i5 = srcs[e + 5], i6 = srcs[e + 6], i7 = srcs[e + 7];
        ushort4 v0 = t4[(size_t)i0 * 16 + lane];
        ushort4 v1 = t4[(size_t)i1 * 16 + lane];
        ushort4 v2 = t4[(size_t)i2 * 16 + lane];
        ushort4 v3 = t4[(size_t)i3 * 16 + lane];
        ushort4 v4 = t4[(size_t)i4 * 16 + lane];
        ushort4 v5 = t4[(size_t)i5 * 16 + lane];
        ushort4 v6 = t4[(size_t)i6 * 16 + lane];
        ushort4 v7 = t4[(size_t)i7 * 16 + lane];
        acc_pk(acc, v0); acc_pk(acc, v1); acc_pk(acc, v2); acc_pk(acc, v3);
        acc_pk(acc, v4); acc_pk(acc, v5); acc_pk(acc, v6); acc_pk(acc, v7);
    }
    for (; e + 3 < s1; e += 4) {
        int i0 = srcs[e], i1 = srcs[e + 1], i2 = srcs[e + 2], i3 = srcs[e + 3];
        ushort4 v0 = t4[(size_t)i0 * 16 + lane];
        ushort4 v1 = t4[(size_t)i1 * 16 + lane];
        ushort4 v2 = t4[(size_t)i2 * 16 + lane];
        ushort4 v3 = t4[(size_t)i3 * 16 + lane];
        acc_pk(acc, v0); acc_pk(acc, v1); acc_pk(acc, v2); acc_pk(acc, v3);
    }
    for (; e < s1; e++) acc_pk(acc, t4[(size_t)srcs[e] * 16 + lane]);
    float d = dis[node];
    float4 b = make_float4(0.f, 0.f, 0.f, 0.f);
    if (bias) b = ((const float4*)bias)[lane];
    pk4 p;
    p.h[0] = (f16)(acc.x * d + b.x); p.h[1] = (f16)(acc.y * d + b.y);
    p.h[2] = (f16)(acc.z * d + b.z); p.h[3] = (f16)(acc.w * d + b.w);
    ((ushort4*)out)[(size_t)node * 16 + lane] = p.u;
}

// ---------------- gemmAB_mfma: hs2 = fp16(dis * ((ag1@W1 + b1) @ W2)) ----------------
// 4 waves/block, 64 rows/block, one 16-row M-tile per wave.
// MFMA 16x16x32_f16 layouts (verified m89/m92): A lane l -> row l&15, k (l>>4)*8..+7
// (contiguous); B via transposed weights wNt[n][k] -> same contiguous pattern;
// D lane l -> col l&15, rows (l>>4)*4 + 0..3.
#define SH_PAD 136      // 64 rows x 136 f16 (pad: 2-way LDS conflicts only; 16B-aligned rows)
__global__ __launch_bounds__(256) void gemmAB_mfma_k(const f16* __restrict__ ag1,
                                                     const f16* __restrict__ w1t,
                                                     const float* __restrict__ b1,
                                                     const f16* __restrict__ w2t,
                                                     const float* __restrict__ dis,
                                                     f16* __restrict__ hs2, int n) {
    __shared__ f16 sH[64 * SH_PAD];               // 17.4KB
    int tid = threadIdx.x;
    int w = tid >> 6, l = tid & 63;
    int cl = l & 15, ko = (l >> 4) * 8, r0 = (l >> 4) * 4;
    int rowbase = blockIdx.x * 64;
    int mrow = rowbase + w * 16;                  // wave's M-tile base row

    // phase 1: H1[64][128] = ag1[64][64] @ W1 + b1   (A-frags direct from global)
    f16x8 a0 = *(const f16x8*)(ag1 + (size_t)(mrow + cl) * 64 + ko);        // k 0..31 slice
    f16x8 a1 = *(const f16x8*)(ag1 + (size_t)(mrow + cl) * 64 + 32 + ko);   // k 32..63 slice
#pragma unroll
    for (int nt = 0; nt < 8; nt++) {
        f32x4 acc = {0.f, 0.f, 0.f, 0.f};
        f16x8 b0 = *(const f16x8*)(w1t + (nt * 16 + cl) * 64 + ko);
        f16x8 b1f = *(const f16x8*)(w1t + (nt * 16 + cl) * 64 + 32 + ko);
        acc = __builtin_amdgcn_mfma_f32_16x16x32_f16(a0, b0, acc, 0, 0, 0);
        acc = __builtin_amdgcn_mfma_f32_16x16x32_f16(a1, b1f, acc, 0, 0, 0);
        float bias = b1[nt * 16 + cl];
#pragma unroll
        for (int j = 0; j < 4; j++)
            sH[(w * 16 + r0 + j) * SH_PAD + nt * 16 + cl] = (f16)(acc[j] + bias);
    }
    __syncthreads();
    // phase 2: hs2[64][64] = dis * (H1 @ W2)
#pragma unroll
    for (int nt = 0; nt < 4; nt++) {
        f32x4 acc = {0.f, 0.f, 0.f, 0.f};
#pragma unroll
        for (int s = 0; s < 4; s++) {
            f16x8 a = *(const f16x8*)(&sH[(w * 16 + cl) * SH_PAD + s * 32 + ko]);
            f16x8 b = *(const f16x8*)(w2t + (nt * 16 + cl) * 128 + s * 32 + ko);
            acc = __builtin_amdgcn_mfma_f32_16x16x32_f16(a, b, acc, 0, 0, 0);
        }
#pragma unroll
        for (int j = 0; j < 4; j++) {
            int row = mrow + r0 + j;
            if (row < n) {
                float d = dis[row];
                hs2[(size_t)row * 64 + nt * 16 + cl] = (f16)(acc[j] * d);
            }
        }
    }
}

// ---------------- batchnorm: per-block partials, NO global atomics ----------------
__global__ __launch_bounds__(256) void bn_part_k(const f16* __restrict__ x, float* __restrict__ pbuf, int n) {
    __shared__ float4 ls[256], lq[256];
    int q = threadIdx.x & 15;     // cols 4q..4q+3
    int rg = threadIdx.x >> 4;    // 0..15
    float4 s = make_float4(0.f, 0.f, 0.f, 0.f);
    float4 ss = make_float4(0.f, 0.f, 0.f, 0.f);
    for (int row = blockIdx.x * 16 + rg; row < n; row += gridDim.x * 16) {
        pk4 p; p.u = ((const ushort4*)x)[(size_t)row * 16 + q];
        float v0 = p.h[0], v1 = p.h[1], v2 = p.h[2], v3 = p.h[3];
        s.x += v0; s.y += v1; s.z += v2; s.w += v3;
        ss.x += v0 * v0; ss.y += v1 * v1; ss.z += v2 * v2; ss.w += v3 * v3;
    }
    ls[threadIdx.x] = s; lq[threadIdx.x] = ss;
    __syncthreads();
    if (threadIdx.x < 16) {
        float4 S = make_float4(0.f, 0.f, 0.f, 0.f);
        float4 Q = make_float4(0.f, 0.f, 0.f, 0.f);
        for (int g = 0; g < 16; g++) {
            float4 a = ls[g * 16 + threadIdx.x], b = lq[g * 16 + threadIdx.x];
            S.x += a.x; S.y += a.y; S.z += a.z; S.w += a.w;
            Q.x += b.x; Q.y += b.y; Q.z += b.z; Q.w += b.w;
        }
        float4* dst = (float4*)(pbuf + (size_t)blockIdx.x * 128);
        dst[threadIdx.x] = S;
        dst[threadIdx.x + 16] = Q;
    }
}

__global__ __launch_bounds__(64) void bn_final_k(const float* __restrict__ pbuf,
                                                 const float* __restrict__ gamma, const float* __restrict__ beta,
                                                 int n, float* __restrict__ scale, float* __restrict__ shift) {
    int c = threadIdx.x;
    float s = 0.f, q = 0.f;
    for (int b = 0; b < BN_NB; b++) {
        s += pbuf[b * 128 + c];
        q += pbuf[b * 128 + 64 + c];
    }
    float inv_n = 1.f / (float)n;
    float mean = s * inv_n;
    float var = q * inv_n - mean * mean;          // biased variance
    float sc = gamma[c] * rsqrtf(var + EPS_BN);
    scale[c] = sc;
    shift[c] = beta[c] - mean * sc;
}

__global__ __launch_bounds__(256) void bn_apply_k(const f16* __restrict__ x, const float* __restrict__ scale,
                                                  const float* __restrict__ shift, float* __restrict__ out, int n) {
    __shared__ float sscale[64], sshift[64];
    if (threadIdx.x < 64) {
        sscale[threadIdx.x] = scale[threadIdx.x];
        sshift[threadIdx.x] = shift[threadIdx.x];
    }
    __syncthreads();
    int i = blockIdx.x * 256 + threadIdx.x;
    if (i < n * 16) {
        int c = (i & 15) * 4;
        pk4 p; p.u = ((const ushort4*)x)[i];
        float4 o;
        o.x = (float)p.h[0] * sscale[c]     + sshift[c];
        o.y = (float)p.h[1] * sscale[c + 1] + sshift[c + 1];
        o.z = (float)p.h[2] * sscale[c + 2] + sshift[c + 2];
        o.w = (float)p.h[3] * sscale[c + 3] + sshift[c + 3];
        ((float4*)out)[i] = o;
    }
}

extern "C" void kernel_launch(void* const* d_in, const int* in_sizes, int n_in,
                              void* d_out, int out_size, void* d_ws, size_t ws_size,
                              hipStream_t stream) {
    const float* emb   = (const float*)d_in[0];
    const float* W1    = (const float*)d_in[1];
    const float* b1    = (const float*)d_in[2];
    const float* W2    = (const float*)d_in[3];
    const float* b2    = (const float*)d_in[4];
    const float* gamma = (const float*)d_in[5];
    const float* beta  = (const float*)d_in[6];
    const int*   ei    = (const int*)d_in[7];     // [2,E] int32
    const int n = in_sizes[0] / 64;               // 100000
    const int E = in_sizes[7] / 2;                // 1600000
    const int* rowv = ei;                         // sources
    const int* colv = ei + E;                     // targets
    const int NBKT = (n + 127) / 128;             // 782

    char* ws = (char*)d_ws;
    size_t o = 0;
    auto alloc = [&](size_t bytes) -> char* {
        char* p = ws + o;
        o = (o + bytes + 255) & ~(size_t)255;
        return p;
    };
    int*   ghist   = (int*)alloc((size_t)SCAT_B * NBKT_PAD * 4);  // 1MB
    int*   bcnt    = (int*)alloc(NBKT_PAD * 4);
    int*   bstart  = (int*)alloc((NBKT_PAD + 1) * 4);
    int*   start   = (int*)alloc((size_t)(n + 1) * 4);
    float* dis     = (float*)alloc((size_t)n * 4);
    int*   srcs    = (int*)alloc((size_t)E * 4);
    float* pbuf    = (float*)alloc(BN_NB * 128 * 4);     // BN partials
    float* bnscale = (float*)alloc(256);
    float* bnshift = (float*)alloc(256);
    f16*   w1t     = (f16*)alloc(128 * 64 * 2);          // W1^T f16 [n][k]
    f16*   w2t     = (f16*)alloc(64 * 128 * 2);          // W2^T f16 [n][k]
    f16*   es      = (f16*)alloc((size_t)n * 64 * 2);    // dis*emb fp16
    f16*   ag1     = (f16*)alloc((size_t)n * 64 * 2);    // layer-1 aggregated
    f16*   hs2     = (f16*)alloc((size_t)n * 64 * 2);    // dis*((ag1@W1+b1)@W2)
    f16*   h2      = (f16*)alloc((size_t)n * 64 * 2);    // pre-BN output
    unsigned* ebuf = (unsigned*)alloc((size_t)E * 4);    // packed bucket edges

    int epb = (E + SCAT_B - 1) / SCAT_B;          // 6250

    hist_k<<<SCAT_B, 1024, 0, stream>>>(colv, E, epb, ghist);
    scan_bucket_k<<<NBKT_PAD, 256, 0, stream>>>(ghist, bcnt);
    scan_total_k<<<1, 1024, 0, stream>>>(bcnt, bstart, start, n, E);
    scatB_k<<<SCAT_B, 1024, 0, stream>>>(rowv, colv, E, epb, ghist, bstart, ebuf);
    buildC_k<<<NBKT, 512, 0, stream>>>(ebuf, bstart, start, srcs, dis, n);

    wprep_k<<<64, 256, 0, stream>>>(W1, W2, w1t, w2t);
    prescale_k<<<(n * 16 + 255) / 256, 256, 0, stream>>>(emb, dis, es, n);
    agg64_k<<<(n + 15) / 16, 256, 0, stream>>>(es, start, srcs, dis, nullptr, ag1, n);
    gemmAB_mfma_k<<<(n + 63) / 64, 256, 0, stream>>>(ag1, w1t, b1, w2t, dis, hs2, n);
    agg64_k<<<(n + 15) / 16, 256, 0, stream>>>(hs2, start, srcs, dis, b2, h2, n);

    bn_part_k<<<BN_NB, 256, 0, stream>>>(h2, pbuf, n);
    bn_final_k<<<1, 64, 0, stream>>>(pbuf, gamma, beta, n, bnscale, bnshift);
    bn_apply_k<<<(n * 16 + 255) / 256, 256, 0, stream>>>(h2, bnscale, bnshift, (float*)d_out, n);
}